// Round 1
// baseline (2401.496 us; speedup 1.0000x reference)
//
#include <hip/hip_runtime.h>
#include <math.h>

namespace {
constexpr int kB = 4, kN = 6, kC = 64, kD = 41, kFH = 16, kFW = 44;
constexpr int kNX0 = 200, kNX1 = 200;
constexpr int kPix = kB * kN * kFH * kFW;        // 16896 pixels
constexpr int kWavesPerBlk = 4;                  // 256-thread blocks, 1 wave = 1 pixel
constexpr int kBlocks = kPix / kWavesPerBlk;     // 4224
}

__device__ __forceinline__ void inv3x3(const float m[9], float inv[9]) {
    float a = m[0], b = m[1], c = m[2];
    float d = m[3], e = m[4], f = m[5];
    float g = m[6], h = m[7], i = m[8];
    float A =  (e * i - f * h);
    float Bm = -(d * i - f * g);
    float Cm =  (d * h - e * g);
    float det = a * A + b * Bm + c * Cm;
    float r = 1.0f / det;
    inv[0] = A * r;
    inv[1] = -(b * i - c * h) * r;
    inv[2] =  (b * f - c * e) * r;
    inv[3] = Bm * r;
    inv[4] =  (a * i - c * g) * r;
    inv[5] = -(a * f - c * d) * r;
    inv[6] = Cm * r;
    inv[7] = -(a * h - b * g) * r;
    inv[8] =  (a * e - b * d) * r;
}

__global__ __launch_bounds__(256) void lss_scatter(
    const float* __restrict__ feat_depth,   // [B,N,D,FH,FW]
    const float* __restrict__ feat_pv,      // [B,N,C,FH,FW]
    const float* __restrict__ rots,         // [B,N,3,3]
    const float* __restrict__ trans,        // [B,N,3]
    const float* __restrict__ intrins,      // [B,N,3,3]
    const float* __restrict__ post_rots,    // [B,N,3,3]
    const float* __restrict__ post_trans,   // [B,N,3]
    float* __restrict__ out)                // [B, C, 200, 200]
{
    const int lane = threadIdx.x & 63;
    const int wave = threadIdx.x >> 6;
    const int pix  = blockIdx.x * kWavesPerBlk + wave;

    const int w  = pix % kFW;
    const int h  = (pix / kFW) % kFH;
    const int bn = pix / (kFW * kFH);
    const int b  = bn / kN;

    // --- per-(b,n) transforms (uniform across wave; cheap, redundant) ---
    const float* R  = rots      + bn * 9;
    const float* K  = intrins   + bn * 9;
    const float* PR = post_rots + bn * 9;
    const float* PT = post_trans + bn * 3;
    const float* T  = trans     + bn * 3;

    float Km[9], PRm[9];
#pragma unroll
    for (int i = 0; i < 9; ++i) { Km[i] = K[i]; PRm[i] = PR[i]; }
    float invK[9], invPR[9];
    inv3x3(Km, invK);
    inv3x3(PRm, invPR);
    float M[9];  // combine = R @ inv(K)
#pragma unroll
    for (int i = 0; i < 3; ++i)
#pragma unroll
        for (int j = 0; j < 3; ++j)
            M[i * 3 + j] = R[i * 3 + 0] * invK[0 * 3 + j]
                         + R[i * 3 + 1] * invK[1 * 3 + j]
                         + R[i * 3 + 2] * invK[2 * 3 + j];
    const float pt0 = PT[0], pt1 = PT[1], pt2 = PT[2];
    const float t0 = T[0], t1 = T[1], t2 = T[2];

    // --- softmax over depth bins (lanes 0..40 hold one bin each) ---
    const int pixBase = h * kFW + w;
    float fd = -INFINITY;
    if (lane < kD)
        fd = feat_depth[(bn * kD + lane) * (kFH * kFW) + pixBase];
    float mx = fd;
#pragma unroll
    for (int off = 32; off >= 1; off >>= 1)
        mx = fmaxf(mx, __shfl_xor(mx, off));
    float ex = (lane < kD) ? __expf(fd - mx) : 0.0f;
    float sm = ex;
#pragma unroll
    for (int off = 32; off >= 1; off >>= 1)
        sm += __shfl_xor(sm, off);
    const float wgt = ex / sm;

    // --- geometry -> voxel index for this lane's depth bin ---
    int vox = -1;
    if (lane < kD) {
        const float u  = (float)w * (703.0f / 43.0f);   // linspace(0, OGW-1, FW)
        const float v  = (float)h * 17.0f;              // linspace(0, OGH-1, FH)
        const float dv = 4.0f + (float)lane;            // arange(4, 45, 1)
        // undo post-transform
        const float px = u - pt0, py = v - pt1, pz = dv - pt2;
        const float ax = invPR[0] * px + invPR[1] * py + invPR[2] * pz;
        const float ay = invPR[3] * px + invPR[4] * py + invPR[5] * pz;
        const float az = invPR[6] * px + invPR[7] * py + invPR[8] * pz;
        // un-project
        const float qx = ax * az, qy = ay * az, qz = az;
        // to ego frame
        const float gx = M[0] * qx + M[1] * qy + M[2] * qz + t0;
        const float gy = M[3] * qx + M[4] * qy + M[5] * qz + t1;
        const float gz = M[6] * qx + M[7] * qy + M[8] * qz + t2;
        // voxelize: (geom - (bx - dx/2)) / dx, truncation toward zero
        const float fx = (gx + 50.0f) / 0.5f;
        const float fy = (gy + 50.0f) / 0.5f;
        const float fz = (gz + 10.0f) / 20.0f;
        const int gix = (int)fx;
        const int giy = (int)fy;
        const int giz = (int)fz;
        if (gix >= 0 && gix < kNX0 && giy >= 0 && giy < kNX1 && giz == 0)
            vox = gix * kNX1 + giy;
    }

    // --- feature for this lane's channel, scatter over depth bins ---
    const float fc = feat_pv[(bn * kC + lane) * (kFH * kFW) + pixBase];
    const int outBase = (b * kC + lane) * (kNX0 * kNX1);

#pragma unroll 1
    for (int d = 0; d < kD; ++d) {
        const int   vd = __shfl(vox, d);
        const float wd = __shfl(wgt, d);
        if (vd >= 0)
            atomicAdd(&out[outBase + vd], wd * fc);
    }
}

extern "C" void kernel_launch(void* const* d_in, const int* in_sizes, int n_in,
                              void* d_out, int out_size, void* d_ws, size_t ws_size,
                              hipStream_t stream) {
    const float* feat_depth = (const float*)d_in[0];
    const float* feat_pv    = (const float*)d_in[1];
    const float* rots       = (const float*)d_in[2];
    const float* trans      = (const float*)d_in[3];
    const float* intrins    = (const float*)d_in[4];
    const float* post_rots  = (const float*)d_in[5];
    const float* post_trans = (const float*)d_in[6];
    float* out = (float*)d_out;

    hipMemsetAsync(out, 0, (size_t)out_size * sizeof(float), stream);

    lss_scatter<<<kBlocks, 256, 0, stream>>>(
        feat_depth, feat_pv, rots, trans, intrins, post_rots, post_trans, out);
}

// Round 2
// 557.462 us; speedup vs baseline: 4.3079x; 4.3079x over previous
//
#include <hip/hip_runtime.h>
#include <math.h>

namespace {
constexpr int kB = 4, kN = 6, kC = 64, kD = 41, kFH = 16, kFW = 44;
constexpr int kNX0 = 200, kNX1 = 200;
constexpr int kPix = kB * kN * kFH * kFW;          // 16896 pixels
constexpr int kPts = kPix * kD;                    // 692736 points
constexpr int kVox = kB * kNX0 * kNX1;             // 160000 voxels
constexpr int kPvElems = kPix * kC;                // 1081344

// ws carve (all sizes multiples of 256B)
constexpr size_t kOffPvT    = 0;
constexpr size_t kSzPvT     = (size_t)kPvElems * 4;          // 4,325,376
constexpr size_t kOffVox    = kOffPvT + kSzPvT;
constexpr size_t kSzVox     = (size_t)kPts * 4;              // 2,770,944
constexpr size_t kOffWgt    = kOffVox + kSzVox;
constexpr size_t kSzWgt     = (size_t)kPts * 4;
constexpr size_t kOffCnt    = kOffWgt + kSzWgt;
constexpr size_t kSzCnt     = (size_t)kVox * 4;              // 640,000
constexpr size_t kOffOffs   = kOffCnt + kSzCnt;
constexpr size_t kSzOffs    = 640256;                        // 160001 u32, padded
constexpr size_t kOffCur    = kOffOffs + kSzOffs;
constexpr size_t kSzCur     = (size_t)kVox * 4;
constexpr size_t kOffSKey   = kOffCur + kSzCur;
constexpr size_t kSzSKey    = (size_t)kPts * 4;
constexpr size_t kOffSWgt   = kOffSKey + kSzSKey;
constexpr size_t kSzSWgt    = (size_t)kPts * 4;
constexpr size_t kWsNeed    = kOffSWgt + kSzSWgt;            // ~17.3 MB
}

__device__ __forceinline__ void inv3x3(const float m[9], float inv[9]) {
    float a = m[0], b = m[1], c = m[2];
    float d = m[3], e = m[4], f = m[5];
    float g = m[6], h = m[7], i = m[8];
    float A =  (e * i - f * h);
    float Bm = -(d * i - f * g);
    float Cm =  (d * h - e * g);
    float det = a * A + b * Bm + c * Cm;
    float r = 1.0f / det;
    inv[0] = A * r;
    inv[1] = -(b * i - c * h) * r;
    inv[2] =  (b * f - c * e) * r;
    inv[3] = Bm * r;
    inv[4] =  (a * i - c * g) * r;
    inv[5] = -(a * f - c * d) * r;
    inv[6] = Cm * r;
    inv[7] = -(a * h - b * g) * r;
    inv[8] =  (a * e - b * d) * r;
}

// ---- K0: transpose feat_pv [bn,C,hw] -> pvT [pix][C] ----
__global__ __launch_bounds__(256) void lss_pvt(const float* __restrict__ pv,
                                               float* __restrict__ pvT) {
    int i = blockIdx.x * 256 + threadIdx.x;
    if (i < kPvElems) {
        int c = i & 63;
        int pix = i >> 6;                 // bn*704 + hw
        int bn = pix / (kFH * kFW), hw = pix % (kFH * kFW);
        pvT[i] = pv[(bn * kC + c) * (kFH * kFW) + hw];
    }
}

// ---- K1: per-pixel softmax + geometry -> (vox, wgt) per point + histogram ----
__global__ __launch_bounds__(256) void lss_geom(
    const float* __restrict__ feat_depth,
    const float* __restrict__ rots,
    const float* __restrict__ trans,
    const float* __restrict__ intrins,
    const float* __restrict__ post_rots,
    const float* __restrict__ post_trans,
    int* __restrict__ voxArr, float* __restrict__ wgtArr,
    unsigned* __restrict__ counts)
{
    const int lane = threadIdx.x & 63;
    const int wave = threadIdx.x >> 6;
    const int pix  = blockIdx.x * 4 + wave;

    const int w  = pix % kFW;
    const int h  = (pix / kFW) % kFH;
    const int bn = pix / (kFW * kFH);
    const int b  = bn / kN;

    const float* R  = rots       + bn * 9;
    const float* K  = intrins    + bn * 9;
    const float* PR = post_rots  + bn * 9;
    const float* PT = post_trans + bn * 3;
    const float* T  = trans      + bn * 3;

    float Km[9], PRm[9];
#pragma unroll
    for (int i = 0; i < 9; ++i) { Km[i] = K[i]; PRm[i] = PR[i]; }
    float invK[9], invPR[9];
    inv3x3(Km, invK);
    inv3x3(PRm, invPR);
    float M[9];
#pragma unroll
    for (int i = 0; i < 3; ++i)
#pragma unroll
        for (int j = 0; j < 3; ++j)
            M[i * 3 + j] = R[i * 3 + 0] * invK[0 * 3 + j]
                         + R[i * 3 + 1] * invK[1 * 3 + j]
                         + R[i * 3 + 2] * invK[2 * 3 + j];
    const float pt0 = PT[0], pt1 = PT[1], pt2 = PT[2];
    const float t0 = T[0], t1 = T[1], t2 = T[2];

    // softmax over depth (lanes 0..40)
    const int pixBase = h * kFW + w;
    float fd = -INFINITY;
    if (lane < kD)
        fd = feat_depth[(bn * kD + lane) * (kFH * kFW) + pixBase];
    float mx = fd;
#pragma unroll
    for (int off = 32; off >= 1; off >>= 1)
        mx = fmaxf(mx, __shfl_xor(mx, off));
    float ex = (lane < kD) ? __expf(fd - mx) : 0.0f;
    float sm = ex;
#pragma unroll
    for (int off = 32; off >= 1; off >>= 1)
        sm += __shfl_xor(sm, off);
    const float wgt = ex / sm;

    if (lane < kD) {
        const float u  = (float)w * (703.0f / 43.0f);
        const float v  = (float)h * 17.0f;
        const float dv = 4.0f + (float)lane;
        const float px = u - pt0, py = v - pt1, pz = dv - pt2;
        const float ax = invPR[0] * px + invPR[1] * py + invPR[2] * pz;
        const float ay = invPR[3] * px + invPR[4] * py + invPR[5] * pz;
        const float az = invPR[6] * px + invPR[7] * py + invPR[8] * pz;
        const float qx = ax * az, qy = ay * az, qz = az;
        const float gx = M[0] * qx + M[1] * qy + M[2] * qz + t0;
        const float gy = M[3] * qx + M[4] * qy + M[5] * qz + t1;
        const float gz = M[6] * qx + M[7] * qy + M[8] * qz + t2;
        const float fx = (gx + 50.0f) / 0.5f;
        const float fy = (gy + 50.0f) / 0.5f;
        const float fz = (gz + 10.0f) / 20.0f;
        const int gix = (int)fx;
        const int giy = (int)fy;
        const int giz = (int)fz;
        int flat = -1;
        if (gix >= 0 && gix < kNX0 && giy >= 0 && giy < kNX1 && giz == 0) {
            flat = (b * kNX0 + gix) * kNX1 + giy;
            atomicAdd(&counts[flat], 1u);
        }
        const int p = pix * kD + lane;
        voxArr[p] = flat;
        wgtArr[p] = wgt;
    }
}

// ---- K2: exclusive scan over 160000 counts (single block) ----
__global__ __launch_bounds__(1024) void lss_scan(const unsigned* __restrict__ counts,
                                                 unsigned* __restrict__ offsets,
                                                 unsigned* __restrict__ cursor) {
    __shared__ unsigned s[1024];
    const int t = threadIdx.x;
    const int chunk = 157;                       // 1024*157 >= 160000
    const int lo = t * chunk;
    const int hi = min(lo + chunk, kVox);
    unsigned sum = 0;
    for (int i = lo; i < hi; ++i) sum += counts[i];
    s[t] = sum;
    __syncthreads();
    for (int o = 1; o < 1024; o <<= 1) {
        unsigned v = (t >= o) ? s[t - o] : 0u;
        __syncthreads();
        s[t] += v;
        __syncthreads();
    }
    unsigned run = s[t] - sum;                   // exclusive base
    for (int i = lo; i < hi; ++i) {
        offsets[i] = run;
        cursor[i]  = run;
        run += counts[i];
    }
    if (t == 1023) offsets[kVox] = run;          // total
}

// ---- K3: scatter points into CSR order ----
__global__ __launch_bounds__(256) void lss_order(const int* __restrict__ voxArr,
                                                 const float* __restrict__ wgtArr,
                                                 unsigned* __restrict__ cursor,
                                                 int* __restrict__ skey,
                                                 float* __restrict__ swgt) {
    const int p = blockIdx.x * 256 + threadIdx.x;
    if (p < kPts) {
        const int f = voxArr[p];
        if (f >= 0) {
            const unsigned slot = atomicAdd(&cursor[f], 1u);
            skey[slot] = p / kD;                 // pix index == pvT row
            swgt[slot] = wgtArr[p];
        }
    }
}

// ---- K4: per-voxel gather, coalesced final write ----
__global__ __launch_bounds__(256) void lss_gather(const float* __restrict__ pvT,
                                                  const unsigned* __restrict__ offsets,
                                                  const int* __restrict__ skey,
                                                  const float* __restrict__ swgt,
                                                  float* __restrict__ out) {
    __shared__ float acc[50][65];                // +1 pad: conflict-free transpose read
    const int tile = blockIdx.x;                 // b*800 + xi*4 + yt
    const int yt = tile & 3;
    const int xi = (tile >> 2) % kNX0;
    const int b  = tile / (kNX0 * 4);
    const int yi0 = yt * 50;
    const int lane = threadIdx.x & 63;
    const int wave = threadIdx.x >> 6;

    for (int j = wave; j < 50; j += 4) {
        const int yi = yi0 + j;
        const int flat = (b * kNX0 + xi) * kNX1 + yi;
        const unsigned s0 = offsets[flat];
        const unsigned e0 = offsets[flat + 1];
        float a = 0.0f;
        for (unsigned base = s0; base < e0; base += 64) {
            const unsigned n = min(64u, e0 - base);
            int k_ = 0; float w_ = 0.0f;
            if (lane < (int)n) {
                k_ = skey[base + lane];
                w_ = swgt[base + lane];
            }
#pragma unroll 4
            for (unsigned k = 0; k < n; ++k) {
                const int pk  = __shfl(k_, (int)k);
                const float wk = __shfl(w_, (int)k);
                a += wk * pvT[pk * kC + lane];   // coalesced 256B per point
            }
        }
        acc[j][lane] = a;
    }
    __syncthreads();

    for (int e = threadIdx.x; e < kC * 50; e += 256) {
        const int c = e / 50, j = e % 50;
        out[((b * kC + c) * (kNX0 * kNX1)) + xi * kNX1 + yi0 + j] = acc[j][c];
    }
}

// ---- fallback: round-1 atomic kernel (used only if ws too small) ----
__global__ __launch_bounds__(256) void lss_scatter_fb(
    const float* __restrict__ feat_depth,
    const float* __restrict__ feat_pv,
    const float* __restrict__ rots,
    const float* __restrict__ trans,
    const float* __restrict__ intrins,
    const float* __restrict__ post_rots,
    const float* __restrict__ post_trans,
    float* __restrict__ out)
{
    const int lane = threadIdx.x & 63;
    const int wave = threadIdx.x >> 6;
    const int pix  = blockIdx.x * 4 + wave;
    const int w  = pix % kFW;
    const int h  = (pix / kFW) % kFH;
    const int bn = pix / (kFW * kFH);
    const int b  = bn / kN;
    const float* R  = rots       + bn * 9;
    const float* K  = intrins    + bn * 9;
    const float* PR = post_rots  + bn * 9;
    const float* PT = post_trans + bn * 3;
    const float* T  = trans      + bn * 3;
    float Km[9], PRm[9];
#pragma unroll
    for (int i = 0; i < 9; ++i) { Km[i] = K[i]; PRm[i] = PR[i]; }
    float invK[9], invPR[9];
    inv3x3(Km, invK);
    inv3x3(PRm, invPR);
    float M[9];
#pragma unroll
    for (int i = 0; i < 3; ++i)
#pragma unroll
        for (int j = 0; j < 3; ++j)
            M[i * 3 + j] = R[i * 3 + 0] * invK[0 * 3 + j]
                         + R[i * 3 + 1] * invK[1 * 3 + j]
                         + R[i * 3 + 2] * invK[2 * 3 + j];
    const float pt0 = PT[0], pt1 = PT[1], pt2 = PT[2];
    const float t0 = T[0], t1 = T[1], t2 = T[2];
    const int pixBase = h * kFW + w;
    float fd = -INFINITY;
    if (lane < kD)
        fd = feat_depth[(bn * kD + lane) * (kFH * kFW) + pixBase];
    float mx = fd;
#pragma unroll
    for (int off = 32; off >= 1; off >>= 1)
        mx = fmaxf(mx, __shfl_xor(mx, off));
    float ex = (lane < kD) ? __expf(fd - mx) : 0.0f;
    float sm = ex;
#pragma unroll
    for (int off = 32; off >= 1; off >>= 1)
        sm += __shfl_xor(sm, off);
    const float wgt = ex / sm;
    int vox = -1;
    if (lane < kD) {
        const float u  = (float)w * (703.0f / 43.0f);
        const float v  = (float)h * 17.0f;
        const float dv = 4.0f + (float)lane;
        const float px = u - pt0, py = v - pt1, pz = dv - pt2;
        const float ax = invPR[0] * px + invPR[1] * py + invPR[2] * pz;
        const float ay = invPR[3] * px + invPR[4] * py + invPR[5] * pz;
        const float az = invPR[6] * px + invPR[7] * py + invPR[8] * pz;
        const float qx = ax * az, qy = ay * az, qz = az;
        const float gx = M[0] * qx + M[1] * qy + M[2] * qz + t0;
        const float gy = M[3] * qx + M[4] * qy + M[5] * qz + t1;
        const float gz = M[6] * qx + M[7] * qy + M[8] * qz + t2;
        const float fx = (gx + 50.0f) / 0.5f;
        const float fy = (gy + 50.0f) / 0.5f;
        const float fz = (gz + 10.0f) / 20.0f;
        const int gix = (int)fx;
        const int giy = (int)fy;
        const int giz = (int)fz;
        if (gix >= 0 && gix < kNX0 && giy >= 0 && giy < kNX1 && giz == 0)
            vox = gix * kNX1 + giy;
    }
    const float fc = feat_pv[(bn * kC + lane) * (kFH * kFW) + pixBase];
    const int outBase = (b * kC + lane) * (kNX0 * kNX1);
#pragma unroll 1
    for (int d = 0; d < kD; ++d) {
        const int   vd = __shfl(vox, d);
        const float wd = __shfl(wgt, d);
        if (vd >= 0)
            atomicAdd(&out[outBase + vd], wd * fc);
    }
}

extern "C" void kernel_launch(void* const* d_in, const int* in_sizes, int n_in,
                              void* d_out, int out_size, void* d_ws, size_t ws_size,
                              hipStream_t stream) {
    const float* feat_depth = (const float*)d_in[0];
    const float* feat_pv    = (const float*)d_in[1];
    const float* rots       = (const float*)d_in[2];
    const float* trans      = (const float*)d_in[3];
    const float* intrins    = (const float*)d_in[4];
    const float* post_rots  = (const float*)d_in[5];
    const float* post_trans = (const float*)d_in[6];
    float* out = (float*)d_out;

    if (ws_size < kWsNeed) {
        // fallback: round-1 atomic path
        hipMemsetAsync(out, 0, (size_t)out_size * sizeof(float), stream);
        lss_scatter_fb<<<kPix / 4, 256, 0, stream>>>(
            feat_depth, feat_pv, rots, trans, intrins, post_rots, post_trans, out);
        return;
    }

    char* ws = (char*)d_ws;
    float*    pvT     = (float*)   (ws + kOffPvT);
    int*      voxArr  = (int*)     (ws + kOffVox);
    float*    wgtArr  = (float*)   (ws + kOffWgt);
    unsigned* counts  = (unsigned*)(ws + kOffCnt);
    unsigned* offsets = (unsigned*)(ws + kOffOffs);
    unsigned* cursor  = (unsigned*)(ws + kOffCur);
    int*      skey    = (int*)     (ws + kOffSKey);
    float*    swgt    = (float*)   (ws + kOffSWgt);

    hipMemsetAsync(counts, 0, kSzCnt, stream);

    lss_pvt<<<kPvElems / 256, 256, 0, stream>>>(feat_pv, pvT);
    lss_geom<<<kPix / 4, 256, 0, stream>>>(
        feat_depth, rots, trans, intrins, post_rots, post_trans,
        voxArr, wgtArr, counts);
    lss_scan<<<1, 1024, 0, stream>>>(counts, offsets, cursor);
    lss_order<<<kPts / 256, 256, 0, stream>>>(voxArr, wgtArr, cursor, skey, swgt);
    lss_gather<<<kB * kNX0 * 4, 256, 0, stream>>>(pvT, offsets, skey, swgt, out);
}

// Round 3
// 203.859 us; speedup vs baseline: 11.7802x; 2.7346x over previous
//
#include <hip/hip_runtime.h>
#include <math.h>

namespace {
constexpr int kB = 4, kN = 6, kC = 64, kD = 41, kFH = 16, kFW = 44;
constexpr int kNX0 = 200, kNX1 = 200;
constexpr int kPix = kB * kN * kFH * kFW;          // 16896 pixels
constexpr int kPts = kPix * kD;                    // 692736 points
constexpr int kVox = kB * kNX0 * kNX1;             // 160000 voxels
constexpr int kPvElems = kPix * kC;                // 1081344
constexpr int kScanBlks = kVox / 256;              // 625 (exact)

// ws carve (aligned chunks)
constexpr size_t kOffPvT    = 0;
constexpr size_t kSzPvT     = (size_t)kPvElems * 4;
constexpr size_t kOffVox    = kOffPvT + kSzPvT;
constexpr size_t kSzVox     = (size_t)kPts * 4;
constexpr size_t kOffWgt    = kOffVox + kSzVox;
constexpr size_t kSzWgt     = (size_t)kPts * 4;
constexpr size_t kOffCnt    = kOffWgt + kSzWgt;
constexpr size_t kSzCnt     = (size_t)kVox * 4;
constexpr size_t kOffOffs   = kOffCnt + kSzCnt;
constexpr size_t kSzOffs    = 640256;              // 160001 u32, padded
constexpr size_t kOffCur    = kOffOffs + kSzOffs;
constexpr size_t kSzCur     = (size_t)kVox * 4;
constexpr size_t kOffBSum   = kOffCur + kSzCur;
constexpr size_t kSzBSum    = 2560;                // 625 u32, padded
constexpr size_t kOffSKey   = kOffBSum + kSzBSum;
constexpr size_t kSzSKey    = (size_t)kPts * 4;
constexpr size_t kOffSWgt   = kOffSKey + kSzSKey;
constexpr size_t kSzSWgt    = (size_t)kPts * 4;
constexpr size_t kWsNeed    = kOffSWgt + kSzSWgt;  // ~17.3 MB
}

__device__ __forceinline__ void inv3x3(const float m[9], float inv[9]) {
    float a = m[0], b = m[1], c = m[2];
    float d = m[3], e = m[4], f = m[5];
    float g = m[6], h = m[7], i = m[8];
    float A =  (e * i - f * h);
    float Bm = -(d * i - f * g);
    float Cm =  (d * h - e * g);
    float det = a * A + b * Bm + c * Cm;
    float r = 1.0f / det;
    inv[0] = A * r;
    inv[1] = -(b * i - c * h) * r;
    inv[2] =  (b * f - c * e) * r;
    inv[3] = Bm * r;
    inv[4] =  (a * i - c * g) * r;
    inv[5] = -(a * f - c * d) * r;
    inv[6] = Cm * r;
    inv[7] = -(a * h - b * g) * r;
    inv[8] =  (a * e - b * d) * r;
}

// ---- K0: transpose feat_pv [bn,C,hw] -> pvT [pix][C] ----
__global__ __launch_bounds__(256) void lss_pvt(const float* __restrict__ pv,
                                               float* __restrict__ pvT) {
    int i = blockIdx.x * 256 + threadIdx.x;
    if (i < kPvElems) {
        int c = i & 63;
        int pix = i >> 6;
        int bn = pix / (kFH * kFW), hw = pix % (kFH * kFW);
        pvT[i] = pv[(bn * kC + c) * (kFH * kFW) + hw];
    }
}

// ---- K1: per-pixel softmax + geometry -> (vox, wgt) per point + histogram ----
__global__ __launch_bounds__(256) void lss_geom(
    const float* __restrict__ feat_depth,
    const float* __restrict__ rots,
    const float* __restrict__ trans,
    const float* __restrict__ intrins,
    const float* __restrict__ post_rots,
    const float* __restrict__ post_trans,
    int* __restrict__ voxArr, float* __restrict__ wgtArr,
    unsigned* __restrict__ counts)
{
    const int lane = threadIdx.x & 63;
    const int wave = threadIdx.x >> 6;
    const int pix  = blockIdx.x * 4 + wave;

    const int w  = pix % kFW;
    const int h  = (pix / kFW) % kFH;
    const int bn = pix / (kFW * kFH);
    const int b  = bn / kN;

    const float* R  = rots       + bn * 9;
    const float* K  = intrins    + bn * 9;
    const float* PR = post_rots  + bn * 9;
    const float* PT = post_trans + bn * 3;
    const float* T  = trans      + bn * 3;

    float Km[9], PRm[9];
#pragma unroll
    for (int i = 0; i < 9; ++i) { Km[i] = K[i]; PRm[i] = PR[i]; }
    float invK[9], invPR[9];
    inv3x3(Km, invK);
    inv3x3(PRm, invPR);
    float M[9];
#pragma unroll
    for (int i = 0; i < 3; ++i)
#pragma unroll
        for (int j = 0; j < 3; ++j)
            M[i * 3 + j] = R[i * 3 + 0] * invK[0 * 3 + j]
                         + R[i * 3 + 1] * invK[1 * 3 + j]
                         + R[i * 3 + 2] * invK[2 * 3 + j];
    const float pt0 = PT[0], pt1 = PT[1], pt2 = PT[2];
    const float t0 = T[0], t1 = T[1], t2 = T[2];

    const int pixBase = h * kFW + w;
    float fd = -INFINITY;
    if (lane < kD)
        fd = feat_depth[(bn * kD + lane) * (kFH * kFW) + pixBase];
    float mx = fd;
#pragma unroll
    for (int off = 32; off >= 1; off >>= 1)
        mx = fmaxf(mx, __shfl_xor(mx, off));
    float ex = (lane < kD) ? __expf(fd - mx) : 0.0f;
    float sm = ex;
#pragma unroll
    for (int off = 32; off >= 1; off >>= 1)
        sm += __shfl_xor(sm, off);
    const float wgt = ex / sm;

    if (lane < kD) {
        const float u  = (float)w * (703.0f / 43.0f);
        const float v  = (float)h * 17.0f;
        const float dv = 4.0f + (float)lane;
        const float px = u - pt0, py = v - pt1, pz = dv - pt2;
        const float ax = invPR[0] * px + invPR[1] * py + invPR[2] * pz;
        const float ay = invPR[3] * px + invPR[4] * py + invPR[5] * pz;
        const float az = invPR[6] * px + invPR[7] * py + invPR[8] * pz;
        const float qx = ax * az, qy = ay * az, qz = az;
        const float gx = M[0] * qx + M[1] * qy + M[2] * qz + t0;
        const float gy = M[3] * qx + M[4] * qy + M[5] * qz + t1;
        const float gz = M[6] * qx + M[7] * qy + M[8] * qz + t2;
        const float fx = (gx + 50.0f) / 0.5f;
        const float fy = (gy + 50.0f) / 0.5f;
        const float fz = (gz + 10.0f) / 20.0f;
        const int gix = (int)fx;
        const int giy = (int)fy;
        const int giz = (int)fz;
        int flat = -1;
        if (gix >= 0 && gix < kNX0 && giy >= 0 && giy < kNX1 && giz == 0) {
            flat = (b * kNX0 + gix) * kNX1 + giy;
            atomicAdd(&counts[flat], 1u);
        }
        const int p = pix * kD + lane;
        voxArr[p] = flat;
        wgtArr[p] = wgt;
    }
}

// ---- K2a: block-local exclusive scan (625 x 256, exact cover) ----
__global__ __launch_bounds__(256) void lss_scan_a(const unsigned* __restrict__ counts,
                                                  unsigned* __restrict__ offsets,
                                                  unsigned* __restrict__ blockSums) {
    const int i = blockIdx.x * 256 + threadIdx.x;
    const int lane = threadIdx.x & 63;
    const int wv = threadIdx.x >> 6;
    const unsigned c = counts[i];
    unsigned s = c;
#pragma unroll
    for (int o = 1; o < 64; o <<= 1) {
        unsigned v = __shfl_up(s, o);
        if (lane >= o) s += v;
    }
    __shared__ unsigned wsum[4];
    if (lane == 63) wsum[wv] = s;
    __syncthreads();
    unsigned base = 0;
#pragma unroll
    for (int k = 0; k < 3; ++k)
        if (k < wv) base += wsum[k];
    const unsigned incl = s + base;
    offsets[i] = incl - c;                      // block-local exclusive
    if (threadIdx.x == 255) blockSums[blockIdx.x] = incl;
}

// ---- K2b: scan 625 block sums (single block), write grand total ----
__global__ __launch_bounds__(1024) void lss_scan_b(unsigned* __restrict__ blockSums,
                                                   unsigned* __restrict__ offsets) {
    const int t = threadIdx.x;
    const int lane = t & 63;
    const int wv = t >> 6;
    const unsigned c = (t < kScanBlks) ? blockSums[t] : 0u;
    unsigned s = c;
#pragma unroll
    for (int o = 1; o < 64; o <<= 1) {
        unsigned v = __shfl_up(s, o);
        if (lane >= o) s += v;
    }
    __shared__ unsigned wsum[16];
    if (lane == 63) wsum[wv] = s;
    __syncthreads();
    unsigned base = 0;
#pragma unroll
    for (int k = 0; k < 15; ++k)
        if (k < wv) base += wsum[k];
    const unsigned incl = s + base;
    if (t < kScanBlks) blockSums[t] = incl - c; // exclusive block base
    if (t == 1023) offsets[kVox] = incl;        // grand total (tail elems are 0)
}

// ---- K2c: add block base, finalize offsets + cursor ----
__global__ __launch_bounds__(256) void lss_scan_c(const unsigned* __restrict__ blockSums,
                                                  unsigned* __restrict__ offsets,
                                                  unsigned* __restrict__ cursor) {
    const int i = blockIdx.x * 256 + threadIdx.x;
    const unsigned v = offsets[i] + blockSums[blockIdx.x];
    offsets[i] = v;
    cursor[i]  = v;
}

// ---- K3: scatter points into CSR order ----
__global__ __launch_bounds__(256) void lss_order(const int* __restrict__ voxArr,
                                                 const float* __restrict__ wgtArr,
                                                 unsigned* __restrict__ cursor,
                                                 int* __restrict__ skey,
                                                 float* __restrict__ swgt) {
    const int p = blockIdx.x * 256 + threadIdx.x;
    if (p < kPts) {
        const int f = voxArr[p];
        if (f >= 0) {
            const unsigned slot = atomicAdd(&cursor[f], 1u);
            skey[slot] = p / kD;
            swgt[slot] = wgtArr[p];
        }
    }
}

// ---- K4: per-voxel gather, coalesced final write ----
__global__ __launch_bounds__(256) void lss_gather(const float* __restrict__ pvT,
                                                  const unsigned* __restrict__ offsets,
                                                  const int* __restrict__ skey,
                                                  const float* __restrict__ swgt,
                                                  float* __restrict__ out) {
    __shared__ float acc[50][65];
    const int tile = blockIdx.x;
    const int yt = tile & 3;
    const int xi = (tile >> 2) % kNX0;
    const int b  = tile / (kNX0 * 4);
    const int yi0 = yt * 50;
    const int lane = threadIdx.x & 63;
    const int wave = threadIdx.x >> 6;

    for (int j = wave; j < 50; j += 4) {
        const int yi = yi0 + j;
        const int flat = (b * kNX0 + xi) * kNX1 + yi;
        const unsigned s0 = offsets[flat];
        const unsigned e0 = offsets[flat + 1];
        float a = 0.0f;
        for (unsigned base = s0; base < e0; base += 64) {
            const unsigned n = min(64u, e0 - base);
            int k_ = 0; float w_ = 0.0f;
            if (lane < (int)n) {
                k_ = skey[base + lane];
                w_ = swgt[base + lane];
            }
#pragma unroll 4
            for (unsigned k = 0; k < n; ++k) {
                const int pk  = __shfl(k_, (int)k);
                const float wk = __shfl(w_, (int)k);
                a += wk * pvT[pk * kC + lane];
            }
        }
        acc[j][lane] = a;
    }
    __syncthreads();

    for (int e = threadIdx.x; e < kC * 50; e += 256) {
        const int c = e / 50, j = e % 50;
        out[((b * kC + c) * (kNX0 * kNX1)) + xi * kNX1 + yi0 + j] = acc[j][c];
    }
}

// ---- fallback: atomic path (used only if ws too small) ----
__global__ __launch_bounds__(256) void lss_scatter_fb(
    const float* __restrict__ feat_depth,
    const float* __restrict__ feat_pv,
    const float* __restrict__ rots,
    const float* __restrict__ trans,
    const float* __restrict__ intrins,
    const float* __restrict__ post_rots,
    const float* __restrict__ post_trans,
    float* __restrict__ out)
{
    const int lane = threadIdx.x & 63;
    const int wave = threadIdx.x >> 6;
    const int pix  = blockIdx.x * 4 + wave;
    const int w  = pix % kFW;
    const int h  = (pix / kFW) % kFH;
    const int bn = pix / (kFW * kFH);
    const int b  = bn / kN;
    const float* R  = rots       + bn * 9;
    const float* K  = intrins    + bn * 9;
    const float* PR = post_rots  + bn * 9;
    const float* PT = post_trans + bn * 3;
    const float* T  = trans      + bn * 3;
    float Km[9], PRm[9];
#pragma unroll
    for (int i = 0; i < 9; ++i) { Km[i] = K[i]; PRm[i] = PR[i]; }
    float invK[9], invPR[9];
    inv3x3(Km, invK);
    inv3x3(PRm, invPR);
    float M[9];
#pragma unroll
    for (int i = 0; i < 3; ++i)
#pragma unroll
        for (int j = 0; j < 3; ++j)
            M[i * 3 + j] = R[i * 3 + 0] * invK[0 * 3 + j]
                         + R[i * 3 + 1] * invK[1 * 3 + j]
                         + R[i * 3 + 2] * invK[2 * 3 + j];
    const float pt0 = PT[0], pt1 = PT[1], pt2 = PT[2];
    const float t0 = T[0], t1 = T[1], t2 = T[2];
    const int pixBase = h * kFW + w;
    float fd = -INFINITY;
    if (lane < kD)
        fd = feat_depth[(bn * kD + lane) * (kFH * kFW) + pixBase];
    float mx = fd;
#pragma unroll
    for (int off = 32; off >= 1; off >>= 1)
        mx = fmaxf(mx, __shfl_xor(mx, off));
    float ex = (lane < kD) ? __expf(fd - mx) : 0.0f;
    float sm = ex;
#pragma unroll
    for (int off = 32; off >= 1; off >>= 1)
        sm += __shfl_xor(sm, off);
    const float wgt = ex / sm;
    int vox = -1;
    if (lane < kD) {
        const float u  = (float)w * (703.0f / 43.0f);
        const float v  = (float)h * 17.0f;
        const float dv = 4.0f + (float)lane;
        const float px = u - pt0, py = v - pt1, pz = dv - pt2;
        const float ax = invPR[0] * px + invPR[1] * py + invPR[2] * pz;
        const float ay = invPR[3] * px + invPR[4] * py + invPR[5] * pz;
        const float az = invPR[6] * px + invPR[7] * py + invPR[8] * pz;
        const float qx = ax * az, qy = ay * az, qz = az;
        const float gx = M[0] * qx + M[1] * qy + M[2] * qz + t0;
        const float gy = M[3] * qx + M[4] * qy + M[5] * qz + t1;
        const float gz = M[6] * qx + M[7] * qy + M[8] * qz + t2;
        const float fx = (gx + 50.0f) / 0.5f;
        const float fy = (gy + 50.0f) / 0.5f;
        const float fz = (gz + 10.0f) / 20.0f;
        const int gix = (int)fx;
        const int giy = (int)fy;
        const int giz = (int)fz;
        if (gix >= 0 && gix < kNX0 && giy >= 0 && giy < kNX1 && giz == 0)
            vox = gix * kNX1 + giy;
    }
    const float fc = feat_pv[(bn * kC + lane) * (kFH * kFW) + pixBase];
    const int outBase = (b * kC + lane) * (kNX0 * kNX1);
#pragma unroll 1
    for (int d = 0; d < kD; ++d) {
        const int   vd = __shfl(vox, d);
        const float wd = __shfl(wgt, d);
        if (vd >= 0)
            atomicAdd(&out[outBase + vd], wd * fc);
    }
}

extern "C" void kernel_launch(void* const* d_in, const int* in_sizes, int n_in,
                              void* d_out, int out_size, void* d_ws, size_t ws_size,
                              hipStream_t stream) {
    const float* feat_depth = (const float*)d_in[0];
    const float* feat_pv    = (const float*)d_in[1];
    const float* rots       = (const float*)d_in[2];
    const float* trans      = (const float*)d_in[3];
    const float* intrins    = (const float*)d_in[4];
    const float* post_rots  = (const float*)d_in[5];
    const float* post_trans = (const float*)d_in[6];
    float* out = (float*)d_out;

    if (ws_size < kWsNeed) {
        hipMemsetAsync(out, 0, (size_t)out_size * sizeof(float), stream);
        lss_scatter_fb<<<kPix / 4, 256, 0, stream>>>(
            feat_depth, feat_pv, rots, trans, intrins, post_rots, post_trans, out);
        return;
    }

    char* ws = (char*)d_ws;
    float*    pvT      = (float*)   (ws + kOffPvT);
    int*      voxArr   = (int*)     (ws + kOffVox);
    float*    wgtArr   = (float*)   (ws + kOffWgt);
    unsigned* counts   = (unsigned*)(ws + kOffCnt);
    unsigned* offsets  = (unsigned*)(ws + kOffOffs);
    unsigned* cursor   = (unsigned*)(ws + kOffCur);
    unsigned* blockSums= (unsigned*)(ws + kOffBSum);
    int*      skey     = (int*)     (ws + kOffSKey);
    float*    swgt     = (float*)   (ws + kOffSWgt);

    hipMemsetAsync(counts, 0, kSzCnt, stream);

    lss_pvt<<<(kPvElems + 255) / 256, 256, 0, stream>>>(feat_pv, pvT);
    lss_geom<<<kPix / 4, 256, 0, stream>>>(
        feat_depth, rots, trans, intrins, post_rots, post_trans,
        voxArr, wgtArr, counts);
    lss_scan_a<<<kScanBlks, 256, 0, stream>>>(counts, offsets, blockSums);
    lss_scan_b<<<1, 1024, 0, stream>>>(blockSums, offsets);
    lss_scan_c<<<kScanBlks, 256, 0, stream>>>(blockSums, offsets, cursor);
    lss_order<<<kPts / 256, 256, 0, stream>>>(voxArr, wgtArr, cursor, skey, swgt);
    lss_gather<<<kB * kNX0 * 4, 256, 0, stream>>>(pvT, offsets, skey, swgt, out);
}